// Round 2
// baseline (487.345 us; speedup 1.0000x reference)
//
#include <hip/hip_runtime.h>

#define NTOK 343
#define NPAD 352
#define DIM 384
#define NHEAD 12
#define HDIM 32
#define NWIN 64
#define BATCH 128
#define SCALE 0.17677669529663687f

typedef __attribute__((ext_vector_type(8))) short bf16x8;
typedef __attribute__((ext_vector_type(4))) short bf16x4;
typedef __attribute__((ext_vector_type(4))) float f32x4;

static __device__ inline short f2bf(float f) {
  union { float f; unsigned u; } v; v.f = f;
  unsigned r = v.u + 0x7fffu + ((v.u >> 16) & 1u);
  return (short)(r >> 16);
}
static __device__ inline float bf2f(short s) {
  union { unsigned u; float f; } v; v.u = ((unsigned)(unsigned short)s) << 16;
  return v.f;
}

#define MFMA16(a, b, c) __builtin_amdgcn_mfma_f32_16x16x32_bf16((a), (b), (c), 0, 0, 0)

// ---------------- kernel 0: bias_full[h][n][m] = bias_table[rpi[n][m]][h] ----
__global__ __launch_bounds__(256) void bias_gather_kernel(
    const float* __restrict__ table, const int* __restrict__ rpi,
    float* __restrict__ bias_full) {
  int idx = blockIdx.x * 256 + threadIdx.x;
  const int total = NHEAD * NTOK * NTOK;
  if (idx >= total) return;
  int h = idx / (NTOK * NTOK);
  int nm = idx - h * (NTOK * NTOK);
  bias_full[idx] = table[rpi[nm] * NHEAD + h];
}

// ---------------- kernel 1: kv = skip @ w_kv^T + b_kv -> K_ws/V_ws (bf16) ----
// grid (6, 343); 128x128 tile, 4 waves each 64x64 (4x4 frags of 16x16x32)
__global__ __launch_bounds__(256) void kv_proj_kernel(
    const float* __restrict__ X, const float* __restrict__ W,
    const float* __restrict__ bkv, short* __restrict__ Kws,
    short* __restrict__ Vws) {
  __shared__ short As[128][40];
  __shared__ short Bs[128][40];
  const int tid = threadIdx.x;
  const int n0 = blockIdx.x * 128;
  const int m0 = blockIdx.y * 128;
  const int lane = tid & 63;
  const int wave = tid >> 6;
  const int wm = (wave >> 1) * 64;
  const int wn = (wave & 1) * 64;
  const int lr = lane & 15;
  const int lk = (lane >> 4) * 8;
  const int c4 = (tid & 7) * 4;
  const int rbase = tid >> 3;

  f32x4 acc[4][4];
#pragma unroll
  for (int m = 0; m < 4; ++m)
#pragma unroll
    for (int n = 0; n < 4; ++n) acc[m][n] = (f32x4){0.f, 0.f, 0.f, 0.f};

  for (int kk = 0; kk < 12; ++kk) {
    __syncthreads();
#pragma unroll
    for (int i = 0; i < 4; ++i) {
      int row = rbase + i * 32;
      f32x4 v = *(const f32x4*)(X + (size_t)(m0 + row) * DIM + kk * 32 + c4);
      bf16x4 s4;
#pragma unroll
      for (int j = 0; j < 4; ++j) s4[j] = f2bf(v[j]);
      *(bf16x4*)(&As[row][c4]) = s4;
    }
#pragma unroll
    for (int i = 0; i < 4; ++i) {
      int row = rbase + i * 32;
      f32x4 v = *(const f32x4*)(W + (size_t)(n0 + row) * DIM + kk * 32 + c4);
      bf16x4 s4;
#pragma unroll
      for (int j = 0; j < 4; ++j) s4[j] = f2bf(v[j]);
      *(bf16x4*)(&Bs[row][c4]) = s4;
    }
    __syncthreads();
    bf16x8 af[4], bf[4];
#pragma unroll
    for (int m = 0; m < 4; ++m) af[m] = *(const bf16x8*)(&As[wm + m * 16 + lr][lk]);
#pragma unroll
    for (int n = 0; n < 4; ++n) bf[n] = *(const bf16x8*)(&Bs[wn + n * 16 + lr][lk]);
#pragma unroll
    for (int m = 0; m < 4; ++m)
#pragma unroll
      for (int n = 0; n < 4; ++n) acc[m][n] = MFMA16(af[m], bf[n], acc[m][n]);
  }

  const int rq = (lane >> 4) * 4;
#pragma unroll
  for (int n = 0; n < 4; ++n) {
    int gcol = n0 + wn + n * 16 + lr;
    float bias = bkv[gcol];
    int c = (gcol >= DIM) ? (gcol - DIM) : gcol;  // FIXED: gcol % 384 (384 != 2^k)
    int h = c >> 5;
    int hd = c & 31;
    short* dst = (gcol < DIM) ? Kws : Vws;
#pragma unroll
    for (int m = 0; m < 4; ++m) {
#pragma unroll
      for (int r = 0; r < 4; ++r) {
        int grow = m0 + wm + m * 16 + rq + r;
        int bb = grow / NTOK;
        int tok = grow - bb * NTOK;
        dst[(((size_t)bb * NHEAD + h) * NTOK + tok) * HDIM + hd] =
            f2bf(acc[m][n][r] + bias);
      }
    }
  }
}

// ---------------- kernel 2: fused attention per (b, h) ----------------------
__global__ __launch_bounds__(256) void attn_kernel(
    const float* __restrict__ x_up, const float* __restrict__ mask,
    const float* __restrict__ bias_full, const short* __restrict__ Kws,
    const short* __restrict__ Vws, short* __restrict__ attn_out) {
  __shared__ short Ksm[NPAD][40];        // K[key][ch], row-pad +8
  __shared__ short Vtsm[HDIM][NPAD + 8]; // V^T[ch][key]
  __shared__ short Psm[4][16][NPAD + 8]; // per-wave P transpose buffer
  const int bid = blockIdx.x;
  const int b = bid / NHEAD;
  const int h = bid - b * NHEAD;
  const int win = b & (NWIN - 1);
  const int tid = threadIdx.x;
  const int wave = tid >> 6;
  const int lane = tid & 63;
  const int lr = lane & 15;
  const int lg = lane >> 4;
  const int koff = lg * 8;

  const short* Kb = Kws + ((size_t)b * NHEAD + h) * NTOK * HDIM;
  const short* Vb = Vws + ((size_t)b * NHEAD + h) * NTOK * HDIM;
  {
    const int c8 = (tid & 3) * 8;
    const int rb = tid >> 2;
    const bf16x8 z8 = {0, 0, 0, 0, 0, 0, 0, 0};
#pragma unroll
    for (int r0 = 0; r0 < 384; r0 += 64) {
      int row = r0 + rb;
      if (row < NPAD) {
        bf16x8 kv = z8;
        if (row < NTOK) kv = *(const bf16x8*)(Kb + row * HDIM + c8);
        *(bf16x8*)(&Ksm[row][c8]) = kv;
      }
    }
#pragma unroll
    for (int r0 = 0; r0 < 384; r0 += 64) {
      int row = r0 + rb;
      if (row < NPAD) {
        bf16x8 vv = z8;
        if (row < NTOK) vv = *(const bf16x8*)(Vb + row * HDIM + c8);
#pragma unroll
        for (int i = 0; i < 8; ++i) Vtsm[c8 + i][row] = vv[i];
      }
    }
  }
  __syncthreads();

  for (int qt = 0; qt < 6; ++qt) {
    const int q0 = qt * 64 + wave * 16;
    if (q0 >= NTOK) continue;
    // Q A-frag: row = lane%16, k = 8*(lane/16)+i  (k = head channel)
    bf16x8 qf = {0, 0, 0, 0, 0, 0, 0, 0};
    const int qrow = q0 + lr;
    if (qrow < NTOK) {
      const float* qp = x_up + ((size_t)b * NTOK + qrow) * DIM + h * HDIM + koff;
      f32x4 v0 = *(const f32x4*)qp;
      f32x4 v1 = *(const f32x4*)(qp + 4);
#pragma unroll
      for (int i = 0; i < 4; ++i) {
        qf[i] = f2bf(v0[i] * SCALE);
        qf[i + 4] = f2bf(v1[i] * SCALE);
      }
    }
    // S = Q @ K^T : 22 col-tiles of 16 keys
    f32x4 s[22];
#pragma unroll
    for (int j = 0; j < 22; ++j) s[j] = (f32x4){0.f, 0.f, 0.f, 0.f};
#pragma unroll
    for (int j = 0; j < 22; ++j) {
      bf16x8 kf = *(const bf16x8*)(&Ksm[j * 16 + lr][koff]);
      s[j] = MFMA16(qf, kf, s[j]);
    }
    // bias + mask + row softmax (rows live in lane>>4 groups; reduce over lane&15)
    const float* bh = bias_full + (size_t)h * NTOK * NTOK;
    const float* mh = mask + (size_t)win * NTOK * NTOK;
#pragma unroll
    for (int r = 0; r < 4; ++r) {
      const int qn = q0 + lg * 4 + r;
      float mx = -1e30f;
      if (qn < NTOK) {
        const float* brow = bh + (size_t)qn * NTOK;
        const float* mrow = mh + (size_t)qn * NTOK;
#pragma unroll
        for (int j = 0; j < 22; ++j) {
          int m = j * 16 + lr;
          float lv = -1e30f;
          if (m < NTOK) lv = s[j][r] + brow[m] + mrow[m];
          s[j][r] = lv;
          mx = fmaxf(mx, lv);
        }
      } else {
#pragma unroll
        for (int j = 0; j < 22; ++j) s[j][r] = -1e30f;
      }
#pragma unroll
      for (int off = 1; off < 16; off <<= 1) mx = fmaxf(mx, __shfl_xor(mx, off));
      float sum = 0.f;
#pragma unroll
      for (int j = 0; j < 22; ++j) {
        float p = __expf(s[j][r] - mx);
        s[j][r] = p;
        sum += p;
      }
#pragma unroll
      for (int off = 1; off < 16; off <<= 1) sum += __shfl_xor(sum, off);
      float inv = 1.0f / sum;
#pragma unroll
      for (int j = 0; j < 22; ++j) s[j][r] *= inv;
    }
    // C-layout -> A-layout transpose of P through LDS
#pragma unroll
    for (int j = 0; j < 22; ++j)
#pragma unroll
      for (int r = 0; r < 4; ++r)
        Psm[wave][lg * 4 + r][j * 16 + lr] = f2bf(s[j][r]);

    // O = P @ V : K dim = keys (11 tiles of 32), 2 col-frags (hd 0..15, 16..31)
    f32x4 o0 = (f32x4){0.f, 0.f, 0.f, 0.f};
    f32x4 o1 = (f32x4){0.f, 0.f, 0.f, 0.f};
#pragma unroll
    for (int kt = 0; kt < 11; ++kt) {
      bf16x8 pf = *(const bf16x8*)(&Psm[wave][lr][kt * 32 + koff]);
      bf16x8 v0 = *(const bf16x8*)(&Vtsm[lr][kt * 32 + koff]);
      bf16x8 v1 = *(const bf16x8*)(&Vtsm[16 + lr][kt * 32 + koff]);
      o0 = MFMA16(pf, v0, o0);
      o1 = MFMA16(pf, v1, o1);
    }
#pragma unroll
    for (int r = 0; r < 4; ++r) {
      int qn = q0 + lg * 4 + r;
      if (qn < NTOK) {
        size_t off = ((size_t)b * NTOK + qn) * DIM + h * HDIM;
        attn_out[off + lr] = f2bf(o0[r]);
        attn_out[off + 16 + lr] = f2bf(o1[r]);
      }
    }
  }
}

// ---------------- kernel 3: out = (attn + pos) @ w_proj^T + b_proj ----------
__global__ __launch_bounds__(256) void out_proj_kernel(
    const short* __restrict__ Xa, const float* __restrict__ pos,
    const float* __restrict__ W, const float* __restrict__ bpr,
    float* __restrict__ out) {
  __shared__ short As[128][40];
  __shared__ short Bs[128][40];
  const int tid = threadIdx.x;
  const int n0 = blockIdx.x * 128;
  const int m0 = blockIdx.y * 128;
  const int lane = tid & 63;
  const int wave = tid >> 6;
  const int wm = (wave >> 1) * 64;
  const int wn = (wave & 1) * 64;
  const int lr = lane & 15;
  const int lk = (lane >> 4) * 8;
  const int c4 = (tid & 7) * 4;
  const int rbase = tid >> 3;

  f32x4 acc[4][4];
#pragma unroll
  for (int m = 0; m < 4; ++m)
#pragma unroll
    for (int n = 0; n < 4; ++n) acc[m][n] = (f32x4){0.f, 0.f, 0.f, 0.f};

  for (int kk = 0; kk < 12; ++kk) {
    __syncthreads();
#pragma unroll
    for (int i = 0; i < 4; ++i) {
      int row = rbase + i * 32;
      size_t goff = (size_t)(m0 + row) * DIM + kk * 32 + c4;
      bf16x4 a4 = *(const bf16x4*)(Xa + goff);
      f32x4 p = *(const f32x4*)(pos + goff);
      bf16x4 s4;
#pragma unroll
      for (int j = 0; j < 4; ++j) s4[j] = f2bf(bf2f(a4[j]) + p[j]);
      *(bf16x4*)(&As[row][c4]) = s4;
    }
#pragma unroll
    for (int i = 0; i < 4; ++i) {
      int row = rbase + i * 32;
      f32x4 v = *(const f32x4*)(W + (size_t)(n0 + row) * DIM + kk * 32 + c4);
      bf16x4 s4;
#pragma unroll
      for (int j = 0; j < 4; ++j) s4[j] = f2bf(v[j]);
      *(bf16x4*)(&Bs[row][c4]) = s4;
    }
    __syncthreads();
    bf16x8 af[4], bf[4];
#pragma unroll
    for (int m = 0; m < 4; ++m) af[m] = *(const bf16x8*)(&As[wm + m * 16 + lr][lk]);
#pragma unroll
    for (int n = 0; n < 4; ++n) bf[n] = *(const bf16x8*)(&Bs[wn + n * 16 + lr][lk]);
#pragma unroll
    for (int m = 0; m < 4; ++m)
#pragma unroll
      for (int n = 0; n < 4; ++n) acc[m][n] = MFMA16(af[m], bf[n], acc[m][n]);
  }

  const int rq = (lane >> 4) * 4;
#pragma unroll
  for (int n = 0; n < 4; ++n) {
    int gcol = n0 + wn + n * 16 + lr;
    float bias = bpr[gcol];
#pragma unroll
    for (int m = 0; m < 4; ++m) {
#pragma unroll
      for (int r = 0; r < 4; ++r) {
        int grow = m0 + wm + m * 16 + rq + r;
        out[(size_t)grow * DIM + gcol] = acc[m][n][r] + bias;
      }
    }
  }
}

extern "C" void kernel_launch(void* const* d_in, const int* in_sizes, int n_in,
                              void* d_out, int out_size, void* d_ws, size_t ws_size,
                              hipStream_t stream) {
  const float* skip = (const float*)d_in[0];
  const float* x_up = (const float*)d_in[1];
  const float* pos = (const float*)d_in[2];
  const float* mask = (const float*)d_in[3];
  const float* w_kv = (const float*)d_in[4];
  const float* b_kv = (const float*)d_in[5];
  const float* w_proj = (const float*)d_in[6];
  const float* b_proj = (const float*)d_in[7];
  const float* bias_table = (const float*)d_in[8];
  const int* rpi = (const int*)d_in[9];
  float* out = (float*)d_out;

  char* ws = (char*)d_ws;
  const size_t kv_bytes = (size_t)BATCH * NHEAD * NTOK * HDIM * 2;     // 33,718,272
  const size_t bias_bytes = (size_t)NHEAD * NTOK * NTOK * 4;           //  5,647,152
  short* Kws = (short*)ws;
  short* Vws = (short*)(ws + kv_bytes);
  float* bias_full = (float*)(ws + 2 * kv_bytes);
  short* attn_ws = (short*)(ws + 2 * kv_bytes + bias_bytes);           // + 33,718,272

  bias_gather_kernel<<<dim3((NHEAD * NTOK * NTOK + 255) / 256), dim3(256), 0,
                       stream>>>(bias_table, rpi, bias_full);
  kv_proj_kernel<<<dim3(6, 343), dim3(256), 0, stream>>>(skip, w_kv, b_kv, Kws, Vws);
  attn_kernel<<<dim3(BATCH * NHEAD), dim3(256), 0, stream>>>(x_up, mask, bias_full,
                                                             Kws, Vws, attn_ws);
  out_proj_kernel<<<dim3(3, 343), dim3(256), 0, stream>>>(attn_ws, pos, w_proj,
                                                          b_proj, out);
}